// Round 1
// baseline (220.730 us; speedup 1.0000x reference)
//
#include <hip/hip_runtime.h>
#include <math.h>

#define B_ 128
#define T_ 256
#define N_ 16
#define K_ 10
#define H_ 20
#define TN_ (T_ * N_)        // 4096
#define S_ (T_ * B_)         // 32768 samples per (k,n): q = tt*128 + b

// ---------------------------------------------------------------------------
// Kernel 1: standardize inputs over batch dim B (ddof=1, no eps).
// x layout: [B][T][N]  (b*4096 + tt*16 + n)
// out xs2 layout: [N][T][B]  so k_mlp reads coalesced and stores coalesced.
// One thread per (tt, n) column; tid = tt*16 + n gives coalesced x reads.
// ---------------------------------------------------------------------------
__global__ void k_std(const float* __restrict__ x, float* __restrict__ xs2)
{
    const int tid = blockIdx.x * blockDim.x + threadIdx.x;   // 0..4095
    const int tt = tid >> 4;
    const int n  = tid & 15;

    float sum = 0.f;
    for (int b = 0; b < B_; ++b) sum += x[b * TN_ + tid];
    const float mu = sum * (1.f / 128.f);

    float ss = 0.f;
    for (int b = 0; b < B_; ++b) {
        const float d = x[b * TN_ + tid] - mu;
        ss = fmaf(d, d, ss);
    }
    const float r = 1.f / sqrtf(ss * (1.f / 127.f));   // ddof=1 -> /127, no eps

    float* col = xs2 + ((size_t)n * T_ + tt) * B_;     // 512B-aligned
    for (int b = 0; b < B_; b += 4) {
        float4 v;
        v.x = (x[(b + 0) * TN_ + tid] - mu) * r;
        v.y = (x[(b + 1) * TN_ + tid] - mu) * r;
        v.z = (x[(b + 2) * TN_ + tid] - mu) * r;
        v.w = (x[(b + 3) * TN_ + tid] - mu) * r;
        *reinterpret_cast<float4*>(col + b) = v;
    }
}

// ---------------------------------------------------------------------------
// Kernel 2: the MLP stack. One block = one (k,n) pair x 1024-sample chunk.
// Each thread processes M=4 samples so each LDS float4 W2 read feeds 4 FMAs.
// tb layout: [K][T][N][B] -> coalesced stores (lane == consecutive b).
// ---------------------------------------------------------------------------
__global__ __launch_bounds__(256, 2) void k_mlp(
    const float* __restrict__ xs2,
    const float* __restrict__ W1, const float* __restrict__ b1,
    const float* __restrict__ W2, const float* __restrict__ b2,
    const float* __restrict__ W3, const float* __restrict__ b3,
    float* __restrict__ tb)
{
    const int kn  = blockIdx.y;          // k*16 + n
    const int k   = kn >> 4;
    const int n   = kn & 15;
    const int tid = threadIdx.x;

    __shared__ float sw1[H_], sb1[H_], sb2[H_], sw3[H_];
    __shared__ float sw2[H_ * H_];
    __shared__ float sb3s;

    if (tid < H_) {
        sw1[tid] = W1[kn * H_ + tid];
        sb1[tid] = b1[kn * H_ + tid];
        sb2[tid] = b2[kn * H_ + tid];
        sw3[tid] = W3[kn * H_ + tid];
    }
    for (int j = tid; j < H_ * H_; j += 256) sw2[j] = W2[kn * H_ * H_ + j];
    if (tid == 0) sb3s = b3[kn];
    __syncthreads();

    const int q0 = blockIdx.x * 1024 + tid;

    float u[4];
#pragma unroll
    for (int m = 0; m < 4; ++m) u[m] = xs2[n * S_ + q0 + m * 256];

    // Layer 1 + LayerNorm 1 (biased var, eps 1e-5)
    float h[4][H_];
#pragma unroll
    for (int m = 0; m < 4; ++m) {
        float s = 0.f;
#pragma unroll
        for (int i = 0; i < H_; ++i) {
            float a = fmaf(u[m], sw1[i], sb1[i]);
            a = fmaxf(a, 0.f);
            h[m][i] = a;
            s += a;
        }
        const float mu = s * (1.f / H_);
        float v = 0.f;
#pragma unroll
        for (int i = 0; i < H_; ++i) { const float d = h[m][i] - mu; v = fmaf(d, d, v); }
        const float r = 1.f / sqrtf(v * (1.f / H_) + 1e-5f);
#pragma unroll
        for (int i = 0; i < H_; ++i) h[m][i] = (h[m][i] - mu) * r;
    }

    // Layer 2 (H x H) + ReLU
    float g[4][H_];
#pragma unroll
    for (int o = 0; o < H_; ++o) {
        float acc[4];
#pragma unroll
        for (int m = 0; m < 4; ++m) acc[m] = sb2[o];
#pragma unroll
        for (int i4 = 0; i4 < H_ / 4; ++i4) {
            const float4 w = *reinterpret_cast<const float4*>(&sw2[o * H_ + i4 * 4]);
            const int i = i4 * 4;
#pragma unroll
            for (int m = 0; m < 4; ++m) {
                acc[m] = fmaf(h[m][i + 0], w.x, acc[m]);
                acc[m] = fmaf(h[m][i + 1], w.y, acc[m]);
                acc[m] = fmaf(h[m][i + 2], w.z, acc[m]);
                acc[m] = fmaf(h[m][i + 3], w.w, acc[m]);
            }
        }
#pragma unroll
        for (int m = 0; m < 4; ++m) g[m][o] = fmaxf(acc[m], 0.f);
    }

    // LayerNorm 2 fused into layer-3 dot, store t
#pragma unroll
    for (int m = 0; m < 4; ++m) {
        float s = 0.f;
#pragma unroll
        for (int i = 0; i < H_; ++i) s += g[m][i];
        const float mu = s * (1.f / H_);
        float v = 0.f;
#pragma unroll
        for (int i = 0; i < H_; ++i) { const float d = g[m][i] - mu; v = fmaf(d, d, v); }
        const float r = 1.f / sqrtf(v * (1.f / H_) + 1e-5f);

        float t = sb3s;
#pragma unroll
        for (int i = 0; i < H_; ++i) t = fmaf((g[m][i] - mu) * r, sw3[i], t);

        const int q  = q0 + m * 256;
        const int tt = q >> 7;       // T index
        const int b  = q & 127;      // B index
        tb[(((size_t)k * T_ + tt) * N_ + n) * B_ + b] = t;
    }
}

// ---------------------------------------------------------------------------
// Kernel 3: per (k,tt): standardize t over B (ddof=1, std + 1e-8), then
// (prod of marginal means - mean of joint products)^2.
// tb: [K][T][N][B]; one block of 128 threads per (k,tt).
// ---------------------------------------------------------------------------
__global__ __launch_bounds__(128) void k_out(const float* __restrict__ tb,
                                             float* __restrict__ okt)
{
    __shared__ float s[N_ * B_];
    __shared__ float cm[N_];
    __shared__ float pjpart[2];

    const int kt  = blockIdx.x;      // k*256 + tt
    const int tid = threadIdx.x;
    const int wv  = tid >> 6;
    const int l   = tid & 63;

    for (int j = tid; j < N_ * B_; j += 128)
        s[j] = tb[(size_t)kt * (N_ * B_) + j];
    __syncthreads();

    // each wave standardizes 8 of the 16 columns
    for (int c = 0; c < 8; ++c) {
        const int n = wv * 8 + c;
        const float a0 = s[n * B_ + l];
        const float a1 = s[n * B_ + 64 + l];

        float sm = a0 + a1;
#pragma unroll
        for (int off = 32; off; off >>= 1) sm += __shfl_xor(sm, off);
        const float mu = sm * (1.f / 128.f);

        const float d0 = a0 - mu, d1 = a1 - mu;
        float vv = fmaf(d0, d0, d1 * d1);
#pragma unroll
        for (int off = 32; off; off >>= 1) vv += __shfl_xor(vv, off);
        const float sd = sqrtf(vv * (1.f / 127.f));       // ddof=1
        const float r  = 1.f / (sd + 1e-8f);              // eps on std

        const float z0 = d0 * r, z1 = d1 * r;
        s[n * B_ + l]      = z0;
        s[n * B_ + 64 + l] = z1;

        float zm = z0 + z1;
#pragma unroll
        for (int off = 32; off; off >>= 1) zm += __shfl_xor(zm, off);
        if (l == 0) cm[n] = zm * (1.f / 128.f);           // marginal mean
    }
    __syncthreads();

    // joint product per b, then mean over b
    float pj = 1.f;
#pragma unroll
    for (int n = 0; n < N_; ++n) pj *= s[n * B_ + tid];
#pragma unroll
    for (int off = 32; off; off >>= 1) pj += __shfl_xor(pj, off);
    if (l == 0) pjpart[wv] = pj;
    __syncthreads();

    if (tid == 0) {
        const float pjm = (pjpart[0] + pjpart[1]) * (1.f / 128.f);
        float pm = 1.f;
        for (int n = 0; n < N_; ++n) pm *= cm[n];
        const float d = pm - pjm;
        okt[kt] = d * d;
    }
}

// ---------------------------------------------------------------------------
// Kernel 4: mean over all (k,t) -> scalar. (mean_k of mean_T == sum/2560)
// ---------------------------------------------------------------------------
__global__ __launch_bounds__(256) void k_red(const float* __restrict__ okt,
                                             float* __restrict__ out)
{
    __shared__ double red[256];
    const int tid = threadIdx.x;
    double a = 0.0;
    for (int j = tid; j < K_ * T_; j += 256) a += (double)okt[j];
    red[tid] = a;
    __syncthreads();
    for (int stp = 128; stp; stp >>= 1) {
        if (tid < stp) red[tid] += red[tid + stp];
        __syncthreads();
    }
    if (tid == 0) out[0] = (float)(red[0] / (double)(K_ * T_));
}

// ---------------------------------------------------------------------------
extern "C" void kernel_launch(void* const* d_in, const int* in_sizes, int n_in,
                              void* d_out, int out_size, void* d_ws, size_t ws_size,
                              hipStream_t stream)
{
    const float* x  = (const float*)d_in[0];
    const float* W1 = (const float*)d_in[1];
    const float* b1 = (const float*)d_in[2];
    const float* W2 = (const float*)d_in[3];
    const float* b2 = (const float*)d_in[4];
    const float* W3 = (const float*)d_in[5];
    const float* b3 = (const float*)d_in[6];
    float* out = (float*)d_out;

    char* ws = (char*)d_ws;
    float* xs2 = (float*)ws;                                   // 2 MB  [N][T][B]
    float* tb  = (float*)(ws + (size_t)2  * 1024 * 1024);      // 20 MB [K][T][N][B]
    float* okt = (float*)(ws + (size_t)23 * 1024 * 1024);      // 10 KB [K*T]

    k_std<<<TN_ / 256, 256, 0, stream>>>(x, xs2);

    dim3 g2(S_ / 1024, K_ * N_);   // 32 chunks x 160 (k,n) pairs
    k_mlp<<<g2, 256, 0, stream>>>(xs2, W1, b1, W2, b2, W3, b3, tb);

    k_out<<<K_ * T_, 128, 0, stream>>>(tb, okt);
    k_red<<<1, 256, 0, stream>>>(okt, out);
}

// Round 2
// 202.961 us; speedup vs baseline: 1.0876x; 1.0876x over previous
//
#include <hip/hip_runtime.h>
#include <math.h>

#define B_ 128
#define T_ 256
#define N_ 16
#define K_ 10
#define H_ 20
#define TN_ (T_ * N_)        // 4096
#define S_ (T_ * B_)         // 32768 samples per (k,n)

__device__ __forceinline__ float wsum(float v)
{
#pragma unroll
    for (int off = 32; off; off >>= 1) v += __shfl_xor(v, off);
    return v;
}

// ---------------------------------------------------------------------------
// Kernel 1: standardize inputs over batch dim B (ddof=1, no eps).
// One WAVE per (tt,n) column: lane l holds b=l and b=64+l, shuffle-reduce.
// x: [B][T][N];  xs2: [N][T][B] (coalesced for k_mlp).
// ---------------------------------------------------------------------------
__global__ __launch_bounds__(256) void k_std(const float* __restrict__ x,
                                             float* __restrict__ xs2)
{
    const int wid = (blockIdx.x * 256 + threadIdx.x) >> 6;   // 0..4095 column
    const int l   = threadIdx.x & 63;
    const int tt  = wid >> 4;
    const int n   = wid & 15;

    const float a0 = x[l * TN_ + wid];
    const float a1 = x[(64 + l) * TN_ + wid];

    const float sm = wsum(a0 + a1);
    const float mu = sm * (1.f / 128.f);

    const float d0 = a0 - mu, d1 = a1 - mu;
    const float vv = wsum(fmaf(d0, d0, d1 * d1));
    const float r  = __builtin_amdgcn_rsqf(vv * (1.f / 127.f));  // ddof=1, no eps

    float* col = xs2 + ((size_t)n * T_ + tt) * B_;
    col[l]      = d0 * r;
    col[64 + l] = d1 * r;
}

// ---------------------------------------------------------------------------
// Kernel 2: the MLP stack. One thread = one sample. All weight reads are
// wave-uniform (blockIdx-derived addresses) -> scalar s_load pipe, no LDS,
// no VALU contention. Consecutive blocks share kn (blockIdx.x fastest) so
// co-resident blocks hit the same K$/L2 weight lines.
// ---------------------------------------------------------------------------
__global__ __launch_bounds__(256) void k_mlp(
    const float* __restrict__ xs2,
    const float* __restrict__ W1, const float* __restrict__ b1,
    const float* __restrict__ W2, const float* __restrict__ b2,
    const float* __restrict__ W3, const float* __restrict__ b3,
    float* __restrict__ tb)
{
    const int kn = blockIdx.y;           // k*16 + n
    const int n  = kn & 15;

    const float* __restrict__ w1  = W1 + kn * H_;
    const float* __restrict__ bb1 = b1 + kn * H_;
    const float* __restrict__ w2  = W2 + kn * H_ * H_;
    const float* __restrict__ bb2 = b2 + kn * H_;
    const float* __restrict__ w3  = W3 + kn * H_;
    const float  bb3 = b3[kn];

    const int q = blockIdx.x * 256 + threadIdx.x;    // 0..32767
    const float u = xs2[n * S_ + q];

    // Layer 1 + LayerNorm 1 (biased var, eps 1e-5)
    float h[H_];
    float s = 0.f;
#pragma unroll
    for (int i = 0; i < H_; ++i) {
        const float a = fmaxf(fmaf(u, w1[i], bb1[i]), 0.f);
        h[i] = a; s += a;
    }
    const float mu = s * (1.f / H_);
    float v = 0.f;
#pragma unroll
    for (int i = 0; i < H_; ++i) { const float d = h[i] - mu; v = fmaf(d, d, v); }
    const float r  = __builtin_amdgcn_rsqf(v * (1.f / H_) + 1e-5f);
    const float mr = mu * r;
#pragma unroll
    for (int i = 0; i < H_; ++i) h[i] = fmaf(h[i], r, -mr);

    // Layer 2 (HxH) + ReLU  — weights via SGPR operands
    float g[H_];
    float s2 = 0.f;
#pragma unroll
    for (int o = 0; o < H_; ++o) {
        float acc = bb2[o];
#pragma unroll
        for (int i = 0; i < H_; ++i) acc = fmaf(h[i], w2[o * H_ + i], acc);
        acc = fmaxf(acc, 0.f);
        g[o] = acc; s2 += acc;
    }

    // LayerNorm 2 fused into layer-3 dot
    const float mu2 = s2 * (1.f / H_);
    float v2 = 0.f;
#pragma unroll
    for (int o = 0; o < H_; ++o) { const float d = g[o] - mu2; v2 = fmaf(d, d, v2); }
    const float r2  = __builtin_amdgcn_rsqf(v2 * (1.f / H_) + 1e-5f);
    const float mr2 = mu2 * r2;

    float t = bb3;
#pragma unroll
    for (int o = 0; o < H_; ++o) t = fmaf(fmaf(g[o], r2, -mr2), w3[o], t);

    const int tt = q >> 7;       // T index
    const int b  = q & 127;      // B index
    tb[(((size_t)kn >> 4) * T_ + tt) * (N_ * B_) + n * B_ + b] = t;
}

// ---------------------------------------------------------------------------
// Kernel 3: one WAVE per (k,tt). Standardize t over B (ddof=1, std+1e-8),
// then (prod marginal means - mean joint product)^2, atomicAdd /2560.
// tb: [K][T][N][B]. d_out must be zeroed before launch (memsetAsync).
// ---------------------------------------------------------------------------
__global__ __launch_bounds__(256) void k_out(const float* __restrict__ tb,
                                             float* __restrict__ out)
{
    const int gw = (blockIdx.x * 256 + threadIdx.x) >> 6;  // 0..2559 (k*256+tt)
    const int l  = threadIdx.x & 63;
    const float* base = tb + (size_t)gw * (N_ * B_);

    float z0[N_], z1[N_], cm[N_];
#pragma unroll
    for (int n = 0; n < N_; ++n) {
        z0[n] = base[n * B_ + l];
        z1[n] = base[n * B_ + 64 + l];
    }
#pragma unroll
    for (int n = 0; n < N_; ++n) {
        const float sm = wsum(z0[n] + z1[n]);
        const float mu = sm * (1.f / 128.f);
        const float d0 = z0[n] - mu, d1 = z1[n] - mu;
        const float vv = wsum(fmaf(d0, d0, d1 * d1));
        const float sd = sqrtf(vv * (1.f / 127.f));        // ddof=1
        const float rr = 1.f / (sd + 1e-8f);               // eps on std
        z0[n] = d0 * rr; z1[n] = d1 * rr;
        cm[n] = wsum(z0[n] + z1[n]) * (1.f / 128.f);       // marginal mean
    }

    float p0 = 1.f, p1 = 1.f;
#pragma unroll
    for (int n = 0; n < N_; ++n) { p0 *= z0[n]; p1 *= z1[n]; }
    const float pj = wsum(p0 + p1) * (1.f / 128.f);

    if (l == 0) {
        float pm = 1.f;
#pragma unroll
        for (int n = 0; n < N_; ++n) pm *= cm[n];
        const float d = pm - pj;
        atomicAdd(out, d * d * (1.f / (K_ * T_)));
    }
}

// ---------------------------------------------------------------------------
extern "C" void kernel_launch(void* const* d_in, const int* in_sizes, int n_in,
                              void* d_out, int out_size, void* d_ws, size_t ws_size,
                              hipStream_t stream)
{
    const float* x  = (const float*)d_in[0];
    const float* W1 = (const float*)d_in[1];
    const float* b1 = (const float*)d_in[2];
    const float* W2 = (const float*)d_in[3];
    const float* b2 = (const float*)d_in[4];
    const float* W3 = (const float*)d_in[5];
    const float* b3 = (const float*)d_in[6];
    float* out = (float*)d_out;

    char* ws = (char*)d_ws;
    float* xs2 = (float*)ws;                                   // 2 MB  [N][T][B]
    float* tb  = (float*)(ws + (size_t)2 * 1024 * 1024);       // 20 MB [K][T][N][B]

    hipMemsetAsync(out, 0, sizeof(float), stream);

    k_std<<<(TN_ * 64) / 256, 256, 0, stream>>>(x, xs2);       // 1024 blocks

    dim3 g2(S_ / 256, K_ * N_);                                // 128 x 160
    k_mlp<<<g2, 256, 0, stream>>>(xs2, W1, b1, W2, b2, W3, b3, tb);

    k_out<<<(K_ * T_ * 64) / 256, 256, 0, stream>>>(tb, out);  // 640 blocks
}

// Round 3
// 199.362 us; speedup vs baseline: 1.1072x; 1.0181x over previous
//
#include <hip/hip_runtime.h>
#include <math.h>

#define B_ 128
#define T_ 256
#define N_ 16
#define K_ 10
#define H_ 20
#define TN_ (T_ * N_)        // 4096
#define S_ (T_ * B_)         // 32768 samples per (k,n)

#define REP20(F) F(0) F(1) F(2) F(3) F(4) F(5) F(6) F(7) F(8) F(9) \
                 F(10) F(11) F(12) F(13) F(14) F(15) F(16) F(17) F(18) F(19)
#define REP16(F) F(0) F(1) F(2) F(3) F(4) F(5) F(6) F(7) F(8) F(9) \
                 F(10) F(11) F(12) F(13) F(14) F(15)

__device__ __forceinline__ float wsum(float v)
{
#pragma unroll
    for (int off = 32; off; off >>= 1) v += __shfl_xor(v, off);
    return v;
}

// ---------------------------------------------------------------------------
// Kernel 1: standardize inputs over batch dim B (ddof=1, no eps).
// One WAVE per (tt,n) column: lane l holds b=l and b=64+l, shuffle-reduce.
// x: [B][T][N];  xs2: [N][T][B] (coalesced for k_mlp).
// ---------------------------------------------------------------------------
__global__ __launch_bounds__(256) void k_std(const float* __restrict__ x,
                                             float* __restrict__ xs2)
{
    const int wid = (blockIdx.x * 256 + threadIdx.x) >> 6;   // 0..4095 column
    const int l   = threadIdx.x & 63;
    const int tt  = wid >> 4;
    const int n   = wid & 15;

    const float a0 = x[l * TN_ + wid];
    const float a1 = x[(64 + l) * TN_ + wid];

    const float sm = wsum(a0 + a1);
    const float mu = sm * (1.f / 128.f);

    const float d0 = a0 - mu, d1 = a1 - mu;
    const float vv = wsum(fmaf(d0, d0, d1 * d1));
    const float r  = __builtin_amdgcn_rsqf(vv * (1.f / 127.f));  // ddof=1, no eps

    float* col = xs2 + ((size_t)n * T_ + tt) * B_;
    col[l]      = d0 * r;
    col[64 + l] = d1 * r;
}

// ---------------------------------------------------------------------------
// Kernel 2: the MLP stack. One thread = one sample. Weights are wave-uniform
// (blockIdx-derived) -> scalar s_load pipe. ALL intermediate state in named
// scalars (h0..h19, g0..g19) so nothing can fall to scratch (VGPR_Count=24
// last round proved the arrays went to local memory).
// ---------------------------------------------------------------------------
__global__ __launch_bounds__(256) void k_mlp(
    const float* __restrict__ xs2,
    const float* __restrict__ W1, const float* __restrict__ b1,
    const float* __restrict__ W2, const float* __restrict__ b2,
    const float* __restrict__ W3, const float* __restrict__ b3,
    float* __restrict__ tb)
{
    const int kn = blockIdx.y;           // k*16 + n
    const int n  = kn & 15;

    const float* __restrict__ w1  = W1 + kn * H_;
    const float* __restrict__ bb1 = b1 + kn * H_;
    const float* __restrict__ w2  = W2 + kn * H_ * H_;
    const float* __restrict__ bb2 = b2 + kn * H_;
    const float* __restrict__ w3  = W3 + kn * H_;
    const float  bb3 = b3[kn];

    const int q = blockIdx.x * 256 + threadIdx.x;    // 0..32767
    const float u = xs2[n * S_ + q];

    // ---- Layer 1 + LayerNorm 1 (biased var, eps 1e-5) ----
#define DECLH(i) float h##i;
    REP20(DECLH)
    float s1 = 0.f;
#define L1(i) h##i = fmaxf(fmaf(u, w1[i], bb1[i]), 0.f); s1 += h##i;
    REP20(L1)
    const float mu1 = s1 * (1.f / H_);
    float v1 = 0.f;
#define VAR1(i) { const float d = h##i - mu1; v1 = fmaf(d, d, v1); }
    REP20(VAR1)
    const float r1  = __builtin_amdgcn_rsqf(v1 * (1.f / H_) + 1e-5f);
    const float mr1 = mu1 * r1;
#define NRM1(i) h##i = fmaf(h##i, r1, -mr1);
    REP20(NRM1)

    // ---- Layer 2 (HxH) + ReLU ----
#define DECLG(i) float g##i;
    REP20(DECLG)
    float s2 = 0.f;
#define L2I(o, i) acc = fmaf(h##i, w2[(o) * 20 + (i)], acc);
#define L2ROW(o) { float acc = bb2[o]; \
    L2I(o,0) L2I(o,1) L2I(o,2) L2I(o,3) L2I(o,4) \
    L2I(o,5) L2I(o,6) L2I(o,7) L2I(o,8) L2I(o,9) \
    L2I(o,10) L2I(o,11) L2I(o,12) L2I(o,13) L2I(o,14) \
    L2I(o,15) L2I(o,16) L2I(o,17) L2I(o,18) L2I(o,19) \
    g##o = fmaxf(acc, 0.f); s2 += g##o; }
    REP20(L2ROW)

    // ---- LayerNorm 2 fused into layer-3 dot ----
    const float mu2 = s2 * (1.f / H_);
    float v2 = 0.f;
#define VAR2(o) { const float d = g##o - mu2; v2 = fmaf(d, d, v2); }
    REP20(VAR2)
    const float r2  = __builtin_amdgcn_rsqf(v2 * (1.f / H_) + 1e-5f);
    const float mr2 = mu2 * r2;

    float t = bb3;
#define L3(o) t = fmaf(fmaf(g##o, r2, -mr2), w3[o], t);
    REP20(L3)

    const int tt = q >> 7;       // T index
    const int b  = q & 127;      // B index
    tb[(((size_t)(kn >> 4) * T_ + tt) * N_ + n) * B_ + b] = t;
}

// ---------------------------------------------------------------------------
// Kernel 3: one WAVE per (k,tt). Standardize t over B (ddof=1, std+1e-8),
// then penalty term. The product of the 16 marginal means (each pure fp32
// rounding residue ~1e-7 after standardization) underflows to exactly 0 in
// the fp32 reference, so (pm - pj)^2 == pj^2. One atomicAdd per wave.
// ---------------------------------------------------------------------------
__global__ __launch_bounds__(256) void k_out(const float* __restrict__ tb,
                                             float* __restrict__ out)
{
    const int gw = (blockIdx.x * 256 + threadIdx.x) >> 6;  // 0..2559 (k*256+tt)
    const int l  = threadIdx.x & 63;
    const float* __restrict__ base = tb + (size_t)gw * (N_ * B_);

#define DECLZ(n) float z0_##n = base[(n) * B_ + l], z1_##n = base[(n) * B_ + 64 + l];
    REP16(DECLZ)

#define STDZ(n) { \
    const float sm = wsum(z0_##n + z1_##n); \
    const float mu = sm * (1.f / 128.f); \
    const float d0 = z0_##n - mu, d1 = z1_##n - mu; \
    const float vv = wsum(fmaf(d0, d0, d1 * d1)); \
    const float rr = 1.f / (sqrtf(vv * (1.f / 127.f)) + 1e-8f); \
    z0_##n = d0 * rr; z1_##n = d1 * rr; }
    REP16(STDZ)

    float p0 = 1.f, p1 = 1.f;
#define PRODZ(n) p0 *= z0_##n; p1 *= z1_##n;
    REP16(PRODZ)
    const float pj = wsum(p0 + p1) * (1.f / 128.f);

    if (l == 0)
        atomicAdd(out, pj * pj * (1.f / (K_ * T_)));
}

// ---------------------------------------------------------------------------
extern "C" void kernel_launch(void* const* d_in, const int* in_sizes, int n_in,
                              void* d_out, int out_size, void* d_ws, size_t ws_size,
                              hipStream_t stream)
{
    const float* x  = (const float*)d_in[0];
    const float* W1 = (const float*)d_in[1];
    const float* b1 = (const float*)d_in[2];
    const float* W2 = (const float*)d_in[3];
    const float* b2 = (const float*)d_in[4];
    const float* W3 = (const float*)d_in[5];
    const float* b3 = (const float*)d_in[6];
    float* out = (float*)d_out;

    char* ws = (char*)d_ws;
    float* xs2 = (float*)ws;                                   // 2 MB  [N][T][B]
    float* tb  = (float*)(ws + (size_t)2 * 1024 * 1024);       // 20 MB [K][T][N][B]

    hipMemsetAsync(out, 0, sizeof(float), stream);

    k_std<<<(TN_ * 64) / 256, 256, 0, stream>>>(x, xs2);       // 1024 blocks

    dim3 g2(S_ / 256, K_ * N_);                                // 128 x 160
    k_mlp<<<g2, 256, 0, stream>>>(xs2, W1, b1, W2, b2, W3, b3, tb);

    k_out<<<(K_ * T_ * 64) / 256, 256, 0, stream>>>(tb, out);  // 640 blocks
}